// Round 6
// baseline (475.748 us; speedup 1.0000x reference)
//
#include <hip/hip_runtime.h>
#include <math.h>

#define NN 50000
#define NP 50176   // NN padded to 392*128 for guard-free GEMM
#define EE 800000
#define ETOT (EE + NN)
#define BB 50
#define PC 16  // pooling chunks per graph

typedef unsigned short u16;
typedef __attribute__((ext_vector_type(8))) short short8;
typedef __attribute__((ext_vector_type(4))) float floatx4;

__device__ __forceinline__ float b2f(u16 u) {
  return __int_as_float(((int)u) << 16);
}
__device__ __forceinline__ u16 f2b(float f) {
  unsigned u = __float_as_uint(f);
  unsigned r = (u + 0x7fffu + ((u >> 16) & 1u)) >> 16;
  return (u16)r;
}
__device__ __forceinline__ float readlane_f(float v, int l) {
  return __int_as_float(__builtin_amdgcn_readlane(__float_as_int(v), l));
}
// bf16 pair -> f32 (1 VALU each)
__device__ __forceinline__ float blo(unsigned w) { return __uint_as_float(w << 16); }
__device__ __forceinline__ float bhi(unsigned w) { return __uint_as_float(w & 0xffff0000u); }

// ---------------- CSR build ----------------
__global__ void count_kernel(const int* __restrict__ ei, int* __restrict__ cnt) {
  int e = blockIdx.x * blockDim.x + threadIdx.x;
  if (e >= ETOT) return;
  int d = (e < EE) ? ei[EE + e] : (e - EE);
  atomicAdd(&cnt[d], 1);
}

// single-block exclusive scan over cnt[NN] -> rowp, rowp[NN] = total
__global__ __launch_bounds__(1024) void scan_kernel(const int* __restrict__ cnt,
                                                    int* __restrict__ rowp) {
  __shared__ int part[1024];
  int t = threadIdx.x;
  int base = t * 49;  // 1024*49 = 50176 >= NN
  int sum = 0;
  for (int i = 0; i < 49; ++i) {
    int idx = base + i;
    if (idx < NN) sum += cnt[idx];
  }
  part[t] = sum;
  __syncthreads();
  for (int off = 1; off < 1024; off <<= 1) {
    int add = (t >= off) ? part[t - off] : 0;
    __syncthreads();
    part[t] += add;
    __syncthreads();
  }
  int run = (t > 0) ? part[t - 1] : 0;
  for (int i = 0; i < 49; ++i) {
    int idx = base + i;
    if (idx < NN) { rowp[idx] = run; run += cnt[idx]; }
  }
  if (t == 1023) rowp[NN] = part[1023];
}

__global__ void fill_kernel(const int* __restrict__ ei, const int* __restrict__ rowp,
                            int* __restrict__ cur, int* __restrict__ col) {
  int e = blockIdx.x * blockDim.x + threadIdx.x;
  if (e >= ETOT) return;
  int s, d;
  if (e < EE) { s = ei[e]; d = ei[EE + e]; } else { s = e - EE; d = s; }
  int p = atomicAdd(&cur[d], 1);
  col[rowp[d] + p] = s;
}

// ---------------- fused dtype prep (xb + W1t + W2t + W3t) ----------------
__global__ void prep_kernel(const float* __restrict__ x, const float* __restrict__ W1,
                            const float* __restrict__ W2, const float* __restrict__ W3,
                            u16* __restrict__ xb, u16* __restrict__ W1t,
                            u16* __restrict__ W2t, u16* __restrict__ W3t) {
  const int T0 = NP * 32, T1 = T0 + 8192, T2 = T1 + 65536, T3 = T2 + 16384;
  int i = blockIdx.x * 256 + threadIdx.x;
  if (i < T0) {
    int n = i >> 5, c = i & 31;
    xb[i] = (n < NN && c < 15) ? f2b(x[n * 15 + c]) : (u16)0;
  } else if (i < T1) {
    int j = i - T0, n = j >> 5, k = j & 31;
    W1t[j] = (k < 15) ? f2b(W1[k * 256 + n]) : (u16)0;
  } else if (i < T2) {
    int j = i - T1, n = j >> 8, k = j & 255;
    W2t[j] = f2b(W2[k * 256 + n]);
  } else if (i < T3) {
    int j = i - T2, n = j >> 8, k = j & 255;
    W3t[j] = f2b(W3[k * 64 + n]);
  }
}

// ---------------- bf16 MFMA GEMM + fused attention-score epilogue ----------------
// C[NP,N] = A[NP,K] @ Bt[N,K]^T.  BM=128, BN=64, template BK (32|64).
// Block (bx,by) covers rows R0..R0+127 and cols of head `by` exactly, so the
// per-node scores as/ad for head by are reduced in-epilogue (shfl + LDS).
template <int BK>
__global__ __launch_bounds__(256) void gemm_bf16_kernel(
    const u16* __restrict__ A, const u16* __restrict__ Bt, u16* __restrict__ C,
    int K, int N, const float* __restrict__ aS, const float* __restrict__ aD,
    float* __restrict__ as_o, float* __restrict__ ad_o, int Hh) {
  __shared__ u16 Al[128][BK + 8];
  __shared__ u16 Bl[64][BK + 8];
  __shared__ float sS[4][64], sD[4][64];
  int R0 = blockIdx.x * 128, C0 = blockIdx.y * 64;
  int wid = threadIdx.x >> 6, lane = threadIdx.x & 63;
  int wr = (wid >> 1) * 64, wc = (wid & 1) * 32;
  int lrow = lane & 15, lk8 = (lane >> 4) * 8;
  int rq = (lane >> 4) * 4;
  const int Q4 = BK / 4;           // ushort4 per row
  const int nA = 128 * Q4, nB = 64 * Q4;
  floatx4 acc[4][2];
#pragma unroll
  for (int i = 0; i < 4; ++i)
#pragma unroll
    for (int j = 0; j < 2; ++j) acc[i][j] = (floatx4){0.f, 0.f, 0.f, 0.f};

  for (int k0 = 0; k0 < K; k0 += BK) {
    for (int c = threadIdx.x; c < nA + nB; c += 256) {
      if (c < nA) {
        int r = c / Q4, o = (c % Q4) * 4;
        *(ushort4*)&Al[r][o] = *(const ushort4*)&A[(size_t)(R0 + r) * K + k0 + o];
      } else {
        int c2 = c - nA;
        int r = c2 / Q4, o = (c2 % Q4) * 4;
        *(ushort4*)&Bl[r][o] = *(const ushort4*)&Bt[(size_t)(C0 + r) * K + k0 + o];
      }
    }
    __syncthreads();
#pragma unroll
    for (int ks = 0; ks < BK / 32; ++ks) {
      short8 a[4], b[2];
#pragma unroll
      for (int i = 0; i < 4; ++i) a[i] = *(const short8*)&Al[wr + i * 16 + lrow][ks * 32 + lk8];
#pragma unroll
      for (int j = 0; j < 2; ++j) b[j] = *(const short8*)&Bl[wc + j * 16 + lrow][ks * 32 + lk8];
#pragma unroll
      for (int i = 0; i < 4; ++i)
#pragma unroll
        for (int j = 0; j < 2; ++j)
          acc[i][j] = __builtin_amdgcn_mfma_f32_16x16x32_bf16(a[i], b[j], acc[i][j], 0, 0, 0);
    }
    __syncthreads();
  }
  // C write (bf16)
#pragma unroll
  for (int i = 0; i < 4; ++i)
#pragma unroll
    for (int j = 0; j < 2; ++j)
#pragma unroll
      for (int q = 0; q < 4; ++q) {
        int gr = R0 + wr + i * 16 + rq + q;
        C[(size_t)gr * N + C0 + wc + j * 16 + lrow] = f2b(acc[i][j][q]);
      }
  // fused score epilogue: per-row dot with aS/aD for head `by`
  int hb = blockIdx.y * 64;
  float wS0 = aS[hb + wc + lrow], wS1 = aS[hb + wc + 16 + lrow];
  float wD0 = aD[hb + wc + lrow], wD1 = aD[hb + wc + 16 + lrow];
#pragma unroll
  for (int i = 0; i < 4; ++i)
#pragma unroll
    for (int q = 0; q < 4; ++q) {
      float vS = acc[i][0][q] * wS0 + acc[i][1][q] * wS1;
      float vD = acc[i][0][q] * wD0 + acc[i][1][q] * wD1;
#pragma unroll
      for (int o = 8; o; o >>= 1) {
        vS += __shfl_xor(vS, o, 64);
        vD += __shfl_xor(vD, o, 64);
      }
      if (lrow == 0) {
        int rl = i * 16 + rq + q;
        sS[wid][rl] = vS;
        sD[wid][rl] = vD;
      }
    }
  __syncthreads();
  if (threadIdx.x < 128) {
    int p = threadIdx.x >> 6, r = threadIdx.x & 63;
    int gr = R0 + p * 64 + r;
    as_o[(size_t)gr * Hh + blockIdx.y] = sS[2 * p][r] + sS[2 * p + 1][r];
    ad_o[(size_t)gr * Hh + blockIdx.y] = sD[2 * p][r] + sD[2 * p + 1][r];
  }
}

// ---------------- single-pass softmax-aggregate, H=4, bf16 h -> bf16 out ----------------
__global__ __launch_bounds__(256) void agg4_kernel(
    const u16* __restrict__ h, const float* __restrict__ as_i,
    const float* __restrict__ ad_i, const int* __restrict__ rowp,
    const int* __restrict__ col, const float* __restrict__ bias,
    u16* __restrict__ xo) {
  __shared__ float exs[4][64][4];  // [wave][edge-slot][head]
  int wid = threadIdx.x >> 6, lane = threadIdx.x & 63;
  int d = blockIdx.x * 4 + wid;
  int rp0 = rowp[d], deg = rowp[d + 1] - rp0;
  float4 add = *(const float4*)&ad_i[(size_t)d * 4];
  int hj = lane >> 4;  // head of this lane's 4 channels
  int lq = lane << 2;  // first channel owned by this lane
  float acc0 = 0.f, acc1 = 0.f, acc2 = 0.f, acc3 = 0.f;
  float den0 = 0.f, den1 = 0.f, den2 = 0.f, den3 = 0.f;

  for (int base = 0; base < deg; base += 64) {
    int i = base + lane;
    bool valid = i < deg;
    int s = valid ? col[rp0 + i] : 0;
    float4 asv = *(const float4*)&as_i[(size_t)s * 4];
    float e0 = asv.x + add.x, e1 = asv.y + add.y, e2 = asv.z + add.z, e3 = asv.w + add.w;
    e0 = (e0 > 0.f) ? e0 : 0.2f * e0;
    e1 = (e1 > 0.f) ? e1 : 0.2f * e1;
    e2 = (e2 > 0.f) ? e2 : 0.2f * e2;
    e3 = (e3 > 0.f) ? e3 : 0.2f * e3;
    float x0 = valid ? __expf(e0) : 0.f;
    float x1 = valid ? __expf(e1) : 0.f;
    float x2 = valid ? __expf(e2) : 0.f;
    float x3 = valid ? __expf(e3) : 0.f;
    den0 += x0; den1 += x1; den2 += x2; den3 += x3;
    *(float4*)&exs[wid][lane][0] = make_float4(x0, x1, x2, x3);
    __threadfence_block();  // order ds_write before the broadcast ds_reads
    int cnt = min(64, deg - base);
    int k4 = cnt & ~3;
    for (int k = 0; k < k4; k += 4) {
      int s0 = __builtin_amdgcn_readlane(s, k);
      int s1 = __builtin_amdgcn_readlane(s, k + 1);
      int s2 = __builtin_amdgcn_readlane(s, k + 2);
      int s3 = __builtin_amdgcn_readlane(s, k + 3);
      float q0 = exs[wid][k][hj];
      float q1 = exs[wid][k + 1][hj];
      float q2 = exs[wid][k + 2][hj];
      float q3 = exs[wid][k + 3][hj];
      uint2 w0 = *(const uint2*)&h[(size_t)s0 * 256 + lq];
      uint2 w1 = *(const uint2*)&h[(size_t)s1 * 256 + lq];
      uint2 w2 = *(const uint2*)&h[(size_t)s2 * 256 + lq];
      uint2 w3 = *(const uint2*)&h[(size_t)s3 * 256 + lq];
      acc0 += q0 * blo(w0.x); acc1 += q0 * bhi(w0.x);
      acc2 += q0 * blo(w0.y); acc3 += q0 * bhi(w0.y);
      acc0 += q1 * blo(w1.x); acc1 += q1 * bhi(w1.x);
      acc2 += q1 * blo(w1.y); acc3 += q1 * bhi(w1.y);
      acc0 += q2 * blo(w2.x); acc1 += q2 * bhi(w2.x);
      acc2 += q2 * blo(w2.y); acc3 += q2 * bhi(w2.y);
      acc0 += q3 * blo(w3.x); acc1 += q3 * bhi(w3.x);
      acc2 += q3 * blo(w3.y); acc3 += q3 * bhi(w3.y);
    }
    for (int k = k4; k < cnt; ++k) {
      int sk = __builtin_amdgcn_readlane(s, k);
      float qk = exs[wid][k][hj];
      uint2 wk = *(const uint2*)&h[(size_t)sk * 256 + lq];
      acc0 += qk * blo(wk.x); acc1 += qk * bhi(wk.x);
      acc2 += qk * blo(wk.y); acc3 += qk * bhi(wk.y);
    }
  }
#pragma unroll
  for (int o = 32; o; o >>= 1) {
    den0 += __shfl_xor(den0, o, 64);
    den1 += __shfl_xor(den1, o, 64);
    den2 += __shfl_xor(den2, o, 64);
    den3 += __shfl_xor(den3, o, 64);
  }
  float den = (hj == 0) ? den0 : (hj == 1) ? den1 : (hj == 2) ? den2 : den3;
  float inv = 1.f / den;
  float4 bv = *(const float4*)&bias[lq];
  float v0 = acc0 * inv + bv.x;
  float v1 = acc1 * inv + bv.y;
  float v2 = acc2 * inv + bv.z;
  float v3 = acc3 * inv + bv.w;
  v0 = (v0 > 0.f) ? v0 : expm1f(v0);
  v1 = (v1 > 0.f) ? v1 : expm1f(v1);
  v2 = (v2 > 0.f) ? v2 : expm1f(v2);
  v3 = (v3 > 0.f) ? v3 : expm1f(v3);
  ushort4 o4;
  o4.x = f2b(v0); o4.y = f2b(v1); o4.z = f2b(v2); o4.w = f2b(v3);
  ((ushort4*)xo)[(size_t)d * 64 + lane] = o4;
}

// ---------------- single-pass softmax-aggregate, H=1, bf16 h -> fp32 out ----------------
__global__ __launch_bounds__(256) void agg1_kernel(
    const u16* __restrict__ h, const float* __restrict__ as_i,
    const float* __restrict__ ad_i, const int* __restrict__ rowp,
    const int* __restrict__ col, const float* __restrict__ bias,
    float* __restrict__ xo) {
  int wid = threadIdx.x >> 6, lane = threadIdx.x & 63;
  int d = blockIdx.x * 4 + wid;
  int rp0 = rowp[d], deg = rowp[d + 1] - rp0;
  float add = ad_i[d];
  float acc = 0.f, den = 0.f;
  for (int base = 0; base < deg; base += 64) {
    int i = base + lane;
    bool valid = i < deg;
    int s = valid ? col[rp0 + i] : 0;
    float e = as_i[s] + add;
    e = (e > 0.f) ? e : 0.2f * e;
    float ex = valid ? __expf(e) : 0.f;
    den += ex;
    int cnt = min(64, deg - base);
    int k8 = cnt & ~7;
    for (int k = 0; k < k8; k += 8) {
      int sA[8];
      float qA[8], hv[8];
#pragma unroll
      for (int u = 0; u < 8; ++u) {
        sA[u] = __builtin_amdgcn_readlane(s, k + u);
        qA[u] = readlane_f(ex, k + u);
      }
#pragma unroll
      for (int u = 0; u < 8; ++u) hv[u] = b2f(h[(size_t)sA[u] * 64 + lane]);
      float p0 = qA[0] * hv[0] + qA[1] * hv[1];
      float p1 = qA[2] * hv[2] + qA[3] * hv[3];
      float p2 = qA[4] * hv[4] + qA[5] * hv[5];
      float p3 = qA[6] * hv[6] + qA[7] * hv[7];
      acc += (p0 + p1) + (p2 + p3);
    }
    for (int k = k8; k < cnt; ++k) {
      int sk = __builtin_amdgcn_readlane(s, k);
      float qk = readlane_f(ex, k);
      acc += qk * b2f(h[(size_t)sk * 64 + lane]);
    }
  }
#pragma unroll
  for (int o = 32; o; o >>= 1) den += __shfl_xor(den, o, 64);
  float v = acc / den + bias[lane];
  v = (v > 0.f) ? v : expm1f(v);
  xo[(size_t)d * 64 + lane] = v;
}

// ---------------- node-attention MLP + fused exp/sum ----------------
__global__ void na_kernel(const float* __restrict__ x3, const float* __restrict__ W1,
                          const float* __restrict__ b1, const float* __restrict__ W2,
                          const float* __restrict__ b2, float* __restrict__ na,
                          float* __restrict__ gsum) {
  __shared__ float Ws[64 * 32];
  __shared__ float W2s[32];
  __shared__ float sred[4];
  for (int i = threadIdx.x; i < 2048; i += blockDim.x) Ws[i] = W1[i];
  if (threadIdx.x < 32) W2s[threadIdx.x] = W2[threadIdx.x];
  __syncthreads();
  int n = blockIdx.x * blockDim.x + threadIdx.x;
  float ez = 0.f;
  if (n < NN) {
    float hid[32];
#pragma unroll
    for (int j = 0; j < 32; ++j) hid[j] = b1[j];
    const float4* x4 = (const float4*)&x3[(size_t)n * 64];
    for (int kk = 0; kk < 16; ++kk) {
      float4 xv = x4[kk];
#pragma unroll
      for (int j = 0; j < 32; ++j) {
        hid[j] += xv.x * Ws[(kk * 4 + 0) * 32 + j];
        hid[j] += xv.y * Ws[(kk * 4 + 1) * 32 + j];
        hid[j] += xv.z * Ws[(kk * 4 + 2) * 32 + j];
        hid[j] += xv.w * Ws[(kk * 4 + 3) * 32 + j];
      }
    }
    float z = b2[0];
#pragma unroll
    for (int j = 0; j < 32; ++j) z += fmaxf(hid[j], 0.f) * W2s[j];
    ez = __expf(z);
    na[n] = ez;
  }
  float acc = ez;
  for (int o = 32; o; o >>= 1) acc += __shfl_xor(acc, o, 64);
  int wid = threadIdx.x >> 6, lane = threadIdx.x & 63;
  if (lane == 0) sred[wid] = acc;
  __syncthreads();
  if (threadIdx.x == 0) atomicAdd(gsum, sred[0] + sred[1] + sred[2] + sred[3]);
}

__global__ void na_write_kernel(const float* __restrict__ na, const float* __restrict__ gsum,
                                float* __restrict__ out) {
  int n = blockIdx.x * blockDim.x + threadIdx.x;
  if (n >= NN) return;
  out[n] = na[n] / gsum[0];
}

// ---------------- pooling stage 1: partial sum/max per (graph, chunk) ----------------
__global__ void pool1_kernel(const float* __restrict__ x3, const int* __restrict__ batch,
                             float* __restrict__ ppsum, float* __restrict__ ppmax) {
  int b = blockIdx.x, c = blockIdx.y;
  int lane = threadIdx.x & 63, wid = threadIdx.x >> 6;
  int lo = 0, hi = NN;
  while (lo < hi) { int m = (lo + hi) >> 1; if (batch[m] < b) lo = m + 1; else hi = m; }
  int start = lo;
  lo = start; hi = NN;
  while (lo < hi) { int m = (lo + hi) >> 1; if (batch[m] < b + 1) lo = m + 1; else hi = m; }
  int end = lo;
  int len = end - start;
  int c0 = start + (int)((long)len * c / PC);
  int c1 = start + (int)((long)len * (c + 1) / PC);
  float acc = 0.f, mx = -INFINITY;
  for (int n = c0 + wid; n < c1; n += 4) {
    float v = x3[(size_t)n * 64 + lane];
    acc += v;
    mx = fmaxf(mx, v);
  }
  __shared__ float ssum[4][64], smax[4][64];
  ssum[wid][lane] = acc;
  smax[wid][lane] = mx;
  __syncthreads();
  if (wid == 0) {
    acc = ssum[0][lane] + ssum[1][lane] + ssum[2][lane] + ssum[3][lane];
    mx = fmaxf(fmaxf(smax[0][lane], smax[1][lane]), fmaxf(smax[2][lane], smax[3][lane]));
    size_t o = ((size_t)c * BB + b) * 64 + lane;
    ppsum[o] = acc;
    ppmax[o] = mx;
  }
}

// ---------------- pooling fold + graph classifier (fused) ----------------
__global__ void pool2cls_kernel(const float* __restrict__ ppsum, const float* __restrict__ ppmax,
                                const int* __restrict__ batch, const float* __restrict__ Wc1,
                                const float* __restrict__ bc1, const float* __restrict__ Wc2,
                                const float* __restrict__ bc2, const float* __restrict__ Wc3,
                                const float* __restrict__ bc3, float* __restrict__ out) {
  __shared__ float g[128], h1[128], h2[64], scnt;
  int b = blockIdx.x, t = threadIdx.x;
  if (t == 0) {
    int lo = 0, hi = NN;
    while (lo < hi) { int m = (lo + hi) >> 1; if (batch[m] < b) lo = m + 1; else hi = m; }
    int start = lo;
    lo = start; hi = NN;
    while (lo < hi) { int m = (lo + hi) >> 1; if (batch[m] < b + 1) lo = m + 1; else hi = m; }
    scnt = (float)(lo - start);
  }
  float s = 0.f, m = -INFINITY;
  if (t < 64) {
#pragma unroll
    for (int c = 0; c < PC; ++c) {
      size_t o = ((size_t)c * BB + b) * 64 + t;
      s += ppsum[o];
      m = fmaxf(m, ppmax[o]);
    }
  }
  __syncthreads();
  float cnt = scnt;
  if (t < 64) {
    g[t] = (cnt > 0.f) ? s / fmaxf(cnt, 1.f) : 0.f;
    g[64 + t] = (cnt > 0.f) ? m : 0.f;
  }
  __syncthreads();
  float v = bc1[t];
  for (int k = 0; k < 128; ++k) v += g[k] * Wc1[k * 128 + t];
  h1[t] = fmaxf(v, 0.f);
  __syncthreads();
  if (t < 64) {
    float v2 = bc2[t];
    for (int k = 0; k < 128; ++k) v2 += h1[k] * Wc2[k * 64 + t];
    h2[t] = fmaxf(v2, 0.f);
  }
  __syncthreads();
  if (t == 0) {
    float z = bc3[0];
    for (int k = 0; k < 64; ++k) z += h2[k] * Wc3[k];
    out[b] = 1.f / (1.f + expf(-z));
  }
}

extern "C" void kernel_launch(void* const* d_in, const int* in_sizes, int n_in,
                              void* d_out, int out_size, void* d_ws, size_t ws_size,
                              hipStream_t stream) {
  const float* x    = (const float*)d_in[0];
  const int*   ei   = (const int*)d_in[1];
  const int*   batch= (const int*)d_in[2];
  const float* W1 = (const float*)d_in[3];
  const float* aS1= (const float*)d_in[4];
  const float* aD1= (const float*)d_in[5];
  const float* b1 = (const float*)d_in[6];
  const float* W2 = (const float*)d_in[7];
  const float* aS2= (const float*)d_in[8];
  const float* aD2= (const float*)d_in[9];
  const float* b2 = (const float*)d_in[10];
  const float* W3 = (const float*)d_in[11];
  const float* aS3= (const float*)d_in[12];
  const float* aD3= (const float*)d_in[13];
  const float* b3 = (const float*)d_in[14];
  const float* Wna1=(const float*)d_in[15];
  const float* bna1=(const float*)d_in[16];
  const float* Wna2=(const float*)d_in[17];
  const float* bna2=(const float*)d_in[18];
  const float* Wc1=(const float*)d_in[19];
  const float* bc1=(const float*)d_in[20];
  const float* Wc2=(const float*)d_in[21];
  const float* bc2=(const float*)d_in[22];
  const float* Wc3=(const float*)d_in[23];
  const float* bc3=(const float*)d_in[24];
  float* out = (float*)d_out;

  // workspace carve-out
  char* w = (char*)d_ws;
  size_t off = 0;
  auto alloc = [&](size_t bytes) {
    void* p = w + off;
    off = (off + bytes + 255) & ~(size_t)255;
    return p;
  };
  u16* xb   = (u16*)alloc((size_t)NP * 32 * 2);        // padded bf16 input
  u16* bufA = (u16*)alloc((size_t)NP * 256 * 2);       // h1 / h2 / h3
  u16* bufB = (u16*)alloc((size_t)NP * 256 * 2);       // y1 / y2 / x3(fp32)
  u16* W1t  = (u16*)alloc((size_t)256 * 32 * 2);
  u16* W2t  = (u16*)alloc((size_t)256 * 256 * 2);
  u16* W3t  = (u16*)alloc((size_t)64 * 256 * 2);
  float* asb  = (float*)alloc((size_t)NP * 4 * 4);
  float* adb  = (float*)alloc((size_t)NP * 4 * 4);
  float* nab  = (float*)alloc((size_t)NN * 4);
  int* rowp = (int*)alloc((size_t)(NN + 1) * 4);
  // cntb, curb, gsum contiguous -> single memset
  int* cntb = (int*)alloc((size_t)NN * 4);
  int* curb = (int*)alloc((size_t)NN * 4);
  float* gsum = (float*)alloc(256);
  size_t zspan = (size_t)((char*)gsum + 256 - (char*)cntb);
  int* colb = (int*)alloc((size_t)ETOT * 4);
  float* ppsum = (float*)alloc((size_t)PC * BB * 64 * 4);
  float* ppmax = (float*)alloc((size_t)PC * BB * 64 * 4);
  float* x3 = (float*)bufB;  // reuse (y2 dead after gemm3)
  (void)ws_size; (void)in_sizes; (void)n_in; (void)out_size;

  hipMemsetAsync(cntb, 0, zspan, stream);

  // CSR by dst (self-loops appended)
  count_kernel<<<(ETOT + 255) / 256, 256, 0, stream>>>(ei, cntb);
  scan_kernel<<<1, 1024, 0, stream>>>(cntb, rowp);
  fill_kernel<<<(ETOT + 255) / 256, 256, 0, stream>>>(ei, rowp, curb, colb);

  // fused dtype prep
  const int PREP_TOT = NP * 32 + 8192 + 65536 + 16384;
  prep_kernel<<<(PREP_TOT + 255) / 256, 256, 0, stream>>>(x, W1, W2, W3, xb, W1t, W2t, W3t);

  const int GX = NP / 128;  // 392
  // layer 1: 15(->32) -> 256  (scores fused into epilogue)
  gemm_bf16_kernel<32><<<dim3(GX, 4), 256, 0, stream>>>(xb, W1t, bufA, 32, 256,
                                                        aS1, aD1, asb, adb, 4);
  agg4_kernel<<<12500, 256, 0, stream>>>(bufA, asb, adb, rowp, colb, b1, bufB);
  // layer 2: 256 -> 256
  gemm_bf16_kernel<64><<<dim3(GX, 4), 256, 0, stream>>>(bufB, W2t, bufA, 256, 256,
                                                        aS2, aD2, asb, adb, 4);
  agg4_kernel<<<12500, 256, 0, stream>>>(bufA, asb, adb, rowp, colb, b2, bufB);
  // layer 3: 256 -> 64
  gemm_bf16_kernel<64><<<dim3(GX, 1), 256, 0, stream>>>(bufB, W3t, bufA, 256, 64,
                                                        aS3, aD3, asb, adb, 1);
  agg1_kernel<<<12500, 256, 0, stream>>>(bufA, asb, adb, rowp, colb, b3, x3);

  // node attention softmax over all N (MLP + exp + sum fused)
  na_kernel<<<(NN + 255) / 256, 256, 0, stream>>>(x3, Wna1, bna1, Wna2, bna2, nab, gsum);
  na_write_kernel<<<(NN + 255) / 256, 256, 0, stream>>>(nab, gsum, out + BB);

  // pooling (two-stage, fold fused with classifier)
  pool1_kernel<<<dim3(BB, PC), 256, 0, stream>>>(x3, batch, ppsum, ppmax);
  pool2cls_kernel<<<BB, 128, 0, stream>>>(ppsum, ppmax, batch, Wc1, bc1, Wc2, bc2,
                                          Wc3, bc3, out);
}

// Round 7
// 391.463 us; speedup vs baseline: 1.2153x; 1.2153x over previous
//
#include <hip/hip_runtime.h>
#include <math.h>

#define NN 50000
#define NP 50176   // NN padded to 392*128 for guard-free GEMM
#define EE 800000
#define ETOT (EE + NN)
#define BB 50
#define PC 16  // pooling chunks per graph

typedef unsigned short u16;
typedef __attribute__((ext_vector_type(8))) short short8;
typedef __attribute__((ext_vector_type(4))) float floatx4;

__device__ __forceinline__ float b2f(u16 u) {
  return __int_as_float(((int)u) << 16);
}
__device__ __forceinline__ u16 f2b(float f) {
  unsigned u = __float_as_uint(f);
  unsigned r = (u + 0x7fffu + ((u >> 16) & 1u)) >> 16;
  return (u16)r;
}
__device__ __forceinline__ float readlane_f(float v, int l) {
  return __int_as_float(__builtin_amdgcn_readlane(__float_as_int(v), l));
}
// bf16 pair -> f32 (1 VALU each)
__device__ __forceinline__ float blo(unsigned w) { return __uint_as_float(w << 16); }
__device__ __forceinline__ float bhi(unsigned w) { return __uint_as_float(w & 0xffff0000u); }

// ---------------- CSR build ----------------
__global__ void count_kernel(const int* __restrict__ ei, int* __restrict__ cnt) {
  int e = blockIdx.x * blockDim.x + threadIdx.x;
  if (e >= ETOT) return;
  int d = (e < EE) ? ei[EE + e] : (e - EE);
  atomicAdd(&cnt[d], 1);
}

// stage 1: block-local exclusive scan (98 blocks x 512)
__global__ void scan1_kernel(const int* __restrict__ cnt, int* __restrict__ rowp,
                             int* __restrict__ part) {
  __shared__ int s[512];
  int t = threadIdx.x;
  int i = blockIdx.x * 512 + t;
  int v = (i < NN) ? cnt[i] : 0;
  s[t] = v;
  __syncthreads();
  for (int off = 1; off < 512; off <<= 1) {
    int add = (t >= off) ? s[t - off] : 0;
    __syncthreads();
    s[t] += add;
    __syncthreads();
  }
  if (i < NN) rowp[i] = s[t] - v;  // exclusive within block
  if (t == 511) part[blockIdx.x] = s[511];
}

// stage 2: parallel scan over the 98 block partials (one 128-thread block)
__global__ void scan2_kernel(int* __restrict__ part, int* __restrict__ rowp) {
  __shared__ int s[128];
  int t = threadIdx.x;
  int v = (t < 98) ? part[t] : 0;
  s[t] = v;
  __syncthreads();
  for (int off = 1; off < 128; off <<= 1) {
    int add = (t >= off) ? s[t - off] : 0;
    __syncthreads();
    s[t] += add;
    __syncthreads();
  }
  if (t < 98) part[t] = s[t] - v;   // exclusive
  if (t == 97) rowp[NN] = s[97];    // total == ETOT
}

// stage 3: add block offset
__global__ void scan3_kernel(int* __restrict__ rowp, const int* __restrict__ part) {
  int i = blockIdx.x * 512 + threadIdx.x;
  if (i < NN) rowp[i] += part[blockIdx.x];
}

__global__ void fill_kernel(const int* __restrict__ ei, const int* __restrict__ rowp,
                            int* __restrict__ cur, int* __restrict__ col) {
  int e = blockIdx.x * blockDim.x + threadIdx.x;
  if (e >= ETOT) return;
  int s, d;
  if (e < EE) { s = ei[e]; d = ei[EE + e]; } else { s = e - EE; d = s; }
  int p = atomicAdd(&cur[d], 1);
  col[rowp[d] + p] = s;
}

// ---------------- fused dtype prep (xb + W1t + W2t + W3t) ----------------
__global__ void prep_kernel(const float* __restrict__ x, const float* __restrict__ W1,
                            const float* __restrict__ W2, const float* __restrict__ W3,
                            u16* __restrict__ xb, u16* __restrict__ W1t,
                            u16* __restrict__ W2t, u16* __restrict__ W3t) {
  const int T0 = NP * 32, T1 = T0 + 8192, T2 = T1 + 65536, T3 = T2 + 16384;
  int i = blockIdx.x * 256 + threadIdx.x;
  if (i < T0) {
    int n = i >> 5, c = i & 31;
    xb[i] = (n < NN && c < 15) ? f2b(x[n * 15 + c]) : (u16)0;
  } else if (i < T1) {
    int j = i - T0, n = j >> 5, k = j & 31;
    W1t[j] = (k < 15) ? f2b(W1[k * 256 + n]) : (u16)0;
  } else if (i < T2) {
    int j = i - T1, n = j >> 8, k = j & 255;
    W2t[j] = f2b(W2[k * 256 + n]);
  } else if (i < T3) {
    int j = i - T2, n = j >> 8, k = j & 255;
    W3t[j] = f2b(W3[k * 64 + n]);
  }
}

// ---------------- bf16 MFMA GEMM + fused attention-score epilogue ----------------
// C[NP,N] = A[NP,K] @ Bt[N,K]^T.  BM=128, BN=64, template BK (32|64).
// Block (bx,by) covers rows R0..R0+127 and cols of head `by` exactly, so the
// per-node scores as/ad for head by are reduced in-epilogue (shfl + LDS).
template <int BK>
__global__ __launch_bounds__(256) void gemm_bf16_kernel(
    const u16* __restrict__ A, const u16* __restrict__ Bt, u16* __restrict__ C,
    int K, int N, const float* __restrict__ aS, const float* __restrict__ aD,
    float* __restrict__ as_o, float* __restrict__ ad_o, int Hh) {
  __shared__ u16 Al[128][BK + 8];
  __shared__ u16 Bl[64][BK + 8];
  __shared__ float sS[4][64], sD[4][64];
  int R0 = blockIdx.x * 128, C0 = blockIdx.y * 64;
  int wid = threadIdx.x >> 6, lane = threadIdx.x & 63;
  int wr = (wid >> 1) * 64, wc = (wid & 1) * 32;
  int lrow = lane & 15, lk8 = (lane >> 4) * 8;
  int rq = (lane >> 4) * 4;
  const int Q4 = BK / 4;           // ushort4 per row
  const int nA = 128 * Q4, nB = 64 * Q4;
  floatx4 acc[4][2];
#pragma unroll
  for (int i = 0; i < 4; ++i)
#pragma unroll
    for (int j = 0; j < 2; ++j) acc[i][j] = (floatx4){0.f, 0.f, 0.f, 0.f};

  for (int k0 = 0; k0 < K; k0 += BK) {
    for (int c = threadIdx.x; c < nA + nB; c += 256) {
      if (c < nA) {
        int r = c / Q4, o = (c % Q4) * 4;
        *(ushort4*)&Al[r][o] = *(const ushort4*)&A[(size_t)(R0 + r) * K + k0 + o];
      } else {
        int c2 = c - nA;
        int r = c2 / Q4, o = (c2 % Q4) * 4;
        *(ushort4*)&Bl[r][o] = *(const ushort4*)&Bt[(size_t)(C0 + r) * K + k0 + o];
      }
    }
    __syncthreads();
#pragma unroll
    for (int ks = 0; ks < BK / 32; ++ks) {
      short8 a[4], b[2];
#pragma unroll
      for (int i = 0; i < 4; ++i) a[i] = *(const short8*)&Al[wr + i * 16 + lrow][ks * 32 + lk8];
#pragma unroll
      for (int j = 0; j < 2; ++j) b[j] = *(const short8*)&Bl[wc + j * 16 + lrow][ks * 32 + lk8];
#pragma unroll
      for (int i = 0; i < 4; ++i)
#pragma unroll
        for (int j = 0; j < 2; ++j)
          acc[i][j] = __builtin_amdgcn_mfma_f32_16x16x32_bf16(a[i], b[j], acc[i][j], 0, 0, 0);
    }
    __syncthreads();
  }
  // C write (bf16)
#pragma unroll
  for (int i = 0; i < 4; ++i)
#pragma unroll
    for (int j = 0; j < 2; ++j)
#pragma unroll
      for (int q = 0; q < 4; ++q) {
        int gr = R0 + wr + i * 16 + rq + q;
        C[(size_t)gr * N + C0 + wc + j * 16 + lrow] = f2b(acc[i][j][q]);
      }
  // fused score epilogue: per-row dot with aS/aD for head `by`
  int hb = blockIdx.y * 64;
  float wS0 = aS[hb + wc + lrow], wS1 = aS[hb + wc + 16 + lrow];
  float wD0 = aD[hb + wc + lrow], wD1 = aD[hb + wc + 16 + lrow];
#pragma unroll
  for (int i = 0; i < 4; ++i)
#pragma unroll
    for (int q = 0; q < 4; ++q) {
      float vS = acc[i][0][q] * wS0 + acc[i][1][q] * wS1;
      float vD = acc[i][0][q] * wD0 + acc[i][1][q] * wD1;
#pragma unroll
      for (int o = 8; o; o >>= 1) {
        vS += __shfl_xor(vS, o, 64);
        vD += __shfl_xor(vD, o, 64);
      }
      if (lrow == 0) {
        int rl = i * 16 + rq + q;
        sS[wid][rl] = vS;
        sD[wid][rl] = vD;
      }
    }
  __syncthreads();
  if (threadIdx.x < 128) {
    int p = threadIdx.x >> 6, r = threadIdx.x & 63;
    int gr = R0 + p * 64 + r;
    as_o[(size_t)gr * Hh + blockIdx.y] = sS[2 * p][r] + sS[2 * p + 1][r];
    ad_o[(size_t)gr * Hh + blockIdx.y] = sD[2 * p][r] + sD[2 * p + 1][r];
  }
}

// ---------------- single-pass softmax-aggregate, H=4, bf16 h -> bf16 out ----------------
__global__ __launch_bounds__(256) void agg4_kernel(
    const u16* __restrict__ h, const float* __restrict__ as_i,
    const float* __restrict__ ad_i, const int* __restrict__ rowp,
    const int* __restrict__ col, const float* __restrict__ bias,
    u16* __restrict__ xo) {
  __shared__ float exs[4][64][4];  // [wave][edge-slot][head]
  int wid = threadIdx.x >> 6, lane = threadIdx.x & 63;
  int d = blockIdx.x * 4 + wid;
  int rp0 = rowp[d], deg = rowp[d + 1] - rp0;
  float4 add = *(const float4*)&ad_i[(size_t)d * 4];
  int hj = lane >> 4;  // head of this lane's 4 channels
  int lq = lane << 2;  // first channel owned by this lane
  float acc0 = 0.f, acc1 = 0.f, acc2 = 0.f, acc3 = 0.f;
  float den0 = 0.f, den1 = 0.f, den2 = 0.f, den3 = 0.f;

  for (int base = 0; base < deg; base += 64) {
    int i = base + lane;
    bool valid = i < deg;
    int s = valid ? col[rp0 + i] : 0;
    float4 asv = *(const float4*)&as_i[(size_t)s * 4];
    float e0 = asv.x + add.x, e1 = asv.y + add.y, e2 = asv.z + add.z, e3 = asv.w + add.w;
    e0 = (e0 > 0.f) ? e0 : 0.2f * e0;
    e1 = (e1 > 0.f) ? e1 : 0.2f * e1;
    e2 = (e2 > 0.f) ? e2 : 0.2f * e2;
    e3 = (e3 > 0.f) ? e3 : 0.2f * e3;
    float x0 = valid ? __expf(e0) : 0.f;
    float x1 = valid ? __expf(e1) : 0.f;
    float x2 = valid ? __expf(e2) : 0.f;
    float x3 = valid ? __expf(e3) : 0.f;
    den0 += x0; den1 += x1; den2 += x2; den3 += x3;
    *(float4*)&exs[wid][lane][0] = make_float4(x0, x1, x2, x3);
    __threadfence_block();  // order ds_write before the broadcast ds_reads
    int cnt = min(64, deg - base);
    int k4 = cnt & ~3;
    for (int k = 0; k < k4; k += 4) {
      int s0 = __builtin_amdgcn_readlane(s, k);
      int s1 = __builtin_amdgcn_readlane(s, k + 1);
      int s2 = __builtin_amdgcn_readlane(s, k + 2);
      int s3 = __builtin_amdgcn_readlane(s, k + 3);
      float q0 = exs[wid][k][hj];
      float q1 = exs[wid][k + 1][hj];
      float q2 = exs[wid][k + 2][hj];
      float q3 = exs[wid][k + 3][hj];
      uint2 w0 = *(const uint2*)&h[(size_t)s0 * 256 + lq];
      uint2 w1 = *(const uint2*)&h[(size_t)s1 * 256 + lq];
      uint2 w2 = *(const uint2*)&h[(size_t)s2 * 256 + lq];
      uint2 w3 = *(const uint2*)&h[(size_t)s3 * 256 + lq];
      acc0 += q0 * blo(w0.x); acc1 += q0 * bhi(w0.x);
      acc2 += q0 * blo(w0.y); acc3 += q0 * bhi(w0.y);
      acc0 += q1 * blo(w1.x); acc1 += q1 * bhi(w1.x);
      acc2 += q1 * blo(w1.y); acc3 += q1 * bhi(w1.y);
      acc0 += q2 * blo(w2.x); acc1 += q2 * bhi(w2.x);
      acc2 += q2 * blo(w2.y); acc3 += q2 * bhi(w2.y);
      acc0 += q3 * blo(w3.x); acc1 += q3 * bhi(w3.x);
      acc2 += q3 * blo(w3.y); acc3 += q3 * bhi(w3.y);
    }
    for (int k = k4; k < cnt; ++k) {
      int sk = __builtin_amdgcn_readlane(s, k);
      float qk = exs[wid][k][hj];
      uint2 wk = *(const uint2*)&h[(size_t)sk * 256 + lq];
      acc0 += qk * blo(wk.x); acc1 += qk * bhi(wk.x);
      acc2 += qk * blo(wk.y); acc3 += qk * bhi(wk.y);
    }
  }
#pragma unroll
  for (int o = 32; o; o >>= 1) {
    den0 += __shfl_xor(den0, o, 64);
    den1 += __shfl_xor(den1, o, 64);
    den2 += __shfl_xor(den2, o, 64);
    den3 += __shfl_xor(den3, o, 64);
  }
  float den = (hj == 0) ? den0 : (hj == 1) ? den1 : (hj == 2) ? den2 : den3;
  float inv = 1.f / den;
  float4 bv = *(const float4*)&bias[lq];
  float v0 = acc0 * inv + bv.x;
  float v1 = acc1 * inv + bv.y;
  float v2 = acc2 * inv + bv.z;
  float v3 = acc3 * inv + bv.w;
  v0 = (v0 > 0.f) ? v0 : expm1f(v0);
  v1 = (v1 > 0.f) ? v1 : expm1f(v1);
  v2 = (v2 > 0.f) ? v2 : expm1f(v2);
  v3 = (v3 > 0.f) ? v3 : expm1f(v3);
  ushort4 o4;
  o4.x = f2b(v0); o4.y = f2b(v1); o4.z = f2b(v2); o4.w = f2b(v3);
  ((ushort4*)xo)[(size_t)d * 64 + lane] = o4;
}

// ---------------- single-pass softmax-aggregate, H=1, bf16 h -> fp32 out ----------------
__global__ __launch_bounds__(256) void agg1_kernel(
    const u16* __restrict__ h, const float* __restrict__ as_i,
    const float* __restrict__ ad_i, const int* __restrict__ rowp,
    const int* __restrict__ col, const float* __restrict__ bias,
    float* __restrict__ xo) {
  int wid = threadIdx.x >> 6, lane = threadIdx.x & 63;
  int d = blockIdx.x * 4 + wid;
  int rp0 = rowp[d], deg = rowp[d + 1] - rp0;
  float add = ad_i[d];
  float acc = 0.f, den = 0.f;
  for (int base = 0; base < deg; base += 64) {
    int i = base + lane;
    bool valid = i < deg;
    int s = valid ? col[rp0 + i] : 0;
    float e = as_i[s] + add;
    e = (e > 0.f) ? e : 0.2f * e;
    float ex = valid ? __expf(e) : 0.f;
    den += ex;
    int cnt = min(64, deg - base);
    int k8 = cnt & ~7;
    for (int k = 0; k < k8; k += 8) {
      int sA[8];
      float qA[8], hv[8];
#pragma unroll
      for (int u = 0; u < 8; ++u) {
        sA[u] = __builtin_amdgcn_readlane(s, k + u);
        qA[u] = readlane_f(ex, k + u);
      }
#pragma unroll
      for (int u = 0; u < 8; ++u) hv[u] = b2f(h[(size_t)sA[u] * 64 + lane]);
      float p0 = qA[0] * hv[0] + qA[1] * hv[1];
      float p1 = qA[2] * hv[2] + qA[3] * hv[3];
      float p2 = qA[4] * hv[4] + qA[5] * hv[5];
      float p3 = qA[6] * hv[6] + qA[7] * hv[7];
      acc += (p0 + p1) + (p2 + p3);
    }
    for (int k = k8; k < cnt; ++k) {
      int sk = __builtin_amdgcn_readlane(s, k);
      float qk = readlane_f(ex, k);
      acc += qk * b2f(h[(size_t)sk * 64 + lane]);
    }
  }
#pragma unroll
  for (int o = 32; o; o >>= 1) den += __shfl_xor(den, o, 64);
  float v = acc / den + bias[lane];
  v = (v > 0.f) ? v : expm1f(v);
  xo[(size_t)d * 64 + lane] = v;
}

// ---------------- node-attention MLP + fused exp/sum ----------------
__global__ void na_kernel(const float* __restrict__ x3, const float* __restrict__ W1,
                          const float* __restrict__ b1, const float* __restrict__ W2,
                          const float* __restrict__ b2, float* __restrict__ na,
                          float* __restrict__ gsum) {
  __shared__ float Ws[64 * 32];
  __shared__ float W2s[32];
  __shared__ float sred[4];
  for (int i = threadIdx.x; i < 2048; i += blockDim.x) Ws[i] = W1[i];
  if (threadIdx.x < 32) W2s[threadIdx.x] = W2[threadIdx.x];
  __syncthreads();
  int n = blockIdx.x * blockDim.x + threadIdx.x;
  float ez = 0.f;
  if (n < NN) {
    float hid[32];
#pragma unroll
    for (int j = 0; j < 32; ++j) hid[j] = b1[j];
    const float4* x4 = (const float4*)&x3[(size_t)n * 64];
    for (int kk = 0; kk < 16; ++kk) {
      float4 xv = x4[kk];
#pragma unroll
      for (int j = 0; j < 32; ++j) {
        hid[j] += xv.x * Ws[(kk * 4 + 0) * 32 + j];
        hid[j] += xv.y * Ws[(kk * 4 + 1) * 32 + j];
        hid[j] += xv.z * Ws[(kk * 4 + 2) * 32 + j];
        hid[j] += xv.w * Ws[(kk * 4 + 3) * 32 + j];
      }
    }
    float z = b2[0];
#pragma unroll
    for (int j = 0; j < 32; ++j) z += fmaxf(hid[j], 0.f) * W2s[j];
    ez = __expf(z);
    na[n] = ez;
  }
  float acc = ez;
  for (int o = 32; o; o >>= 1) acc += __shfl_xor(acc, o, 64);
  int wid = threadIdx.x >> 6, lane = threadIdx.x & 63;
  if (lane == 0) sred[wid] = acc;
  __syncthreads();
  if (threadIdx.x == 0) atomicAdd(gsum, sred[0] + sred[1] + sred[2] + sred[3]);
}

__global__ void na_write_kernel(const float* __restrict__ na, const float* __restrict__ gsum,
                                float* __restrict__ out) {
  int n = blockIdx.x * blockDim.x + threadIdx.x;
  if (n >= NN) return;
  out[n] = na[n] / gsum[0];
}

// ---------------- pooling stage 1: partial sum/max per (graph, chunk) ----------------
__global__ void pool1_kernel(const float* __restrict__ x3, const int* __restrict__ batch,
                             float* __restrict__ ppsum, float* __restrict__ ppmax) {
  int b = blockIdx.x, c = blockIdx.y;
  int lane = threadIdx.x & 63, wid = threadIdx.x >> 6;
  int lo = 0, hi = NN;
  while (lo < hi) { int m = (lo + hi) >> 1; if (batch[m] < b) lo = m + 1; else hi = m; }
  int start = lo;
  lo = start; hi = NN;
  while (lo < hi) { int m = (lo + hi) >> 1; if (batch[m] < b + 1) lo = m + 1; else hi = m; }
  int end = lo;
  int len = end - start;
  int c0 = start + (int)((long)len * c / PC);
  int c1 = start + (int)((long)len * (c + 1) / PC);
  float acc = 0.f, mx = -INFINITY;
  for (int n = c0 + wid; n < c1; n += 4) {
    float v = x3[(size_t)n * 64 + lane];
    acc += v;
    mx = fmaxf(mx, v);
  }
  __shared__ float ssum[4][64], smax[4][64];
  ssum[wid][lane] = acc;
  smax[wid][lane] = mx;
  __syncthreads();
  if (wid == 0) {
    acc = ssum[0][lane] + ssum[1][lane] + ssum[2][lane] + ssum[3][lane];
    mx = fmaxf(fmaxf(smax[0][lane], smax[1][lane]), fmaxf(smax[2][lane], smax[3][lane]));
    size_t o = ((size_t)c * BB + b) * 64 + lane;
    ppsum[o] = acc;
    ppmax[o] = mx;
  }
}

// ---------------- pooling fold + graph classifier (fused) ----------------
__global__ void pool2cls_kernel(const float* __restrict__ ppsum, const float* __restrict__ ppmax,
                                const int* __restrict__ batch, const float* __restrict__ Wc1,
                                const float* __restrict__ bc1, const float* __restrict__ Wc2,
                                const float* __restrict__ bc2, const float* __restrict__ Wc3,
                                const float* __restrict__ bc3, float* __restrict__ out) {
  __shared__ float g[128], h1[128], h2[64], scnt;
  int b = blockIdx.x, t = threadIdx.x;
  if (t == 0) {
    int lo = 0, hi = NN;
    while (lo < hi) { int m = (lo + hi) >> 1; if (batch[m] < b) lo = m + 1; else hi = m; }
    int start = lo;
    lo = start; hi = NN;
    while (lo < hi) { int m = (lo + hi) >> 1; if (batch[m] < b + 1) lo = m + 1; else hi = m; }
    scnt = (float)(lo - start);
  }
  float s = 0.f, m = -INFINITY;
  if (t < 64) {
#pragma unroll
    for (int c = 0; c < PC; ++c) {
      size_t o = ((size_t)c * BB + b) * 64 + t;
      s += ppsum[o];
      m = fmaxf(m, ppmax[o]);
    }
  }
  __syncthreads();
  float cnt = scnt;
  if (t < 64) {
    g[t] = (cnt > 0.f) ? s / fmaxf(cnt, 1.f) : 0.f;
    g[64 + t] = (cnt > 0.f) ? m : 0.f;
  }
  __syncthreads();
  float v = bc1[t];
  for (int k = 0; k < 128; ++k) v += g[k] * Wc1[k * 128 + t];
  h1[t] = fmaxf(v, 0.f);
  __syncthreads();
  if (t < 64) {
    float v2 = bc2[t];
    for (int k = 0; k < 128; ++k) v2 += h1[k] * Wc2[k * 64 + t];
    h2[t] = fmaxf(v2, 0.f);
  }
  __syncthreads();
  if (t == 0) {
    float z = bc3[0];
    for (int k = 0; k < 64; ++k) z += h2[k] * Wc3[k];
    out[b] = 1.f / (1.f + expf(-z));
  }
}

extern "C" void kernel_launch(void* const* d_in, const int* in_sizes, int n_in,
                              void* d_out, int out_size, void* d_ws, size_t ws_size,
                              hipStream_t stream) {
  const float* x    = (const float*)d_in[0];
  const int*   ei   = (const int*)d_in[1];
  const int*   batch= (const int*)d_in[2];
  const float* W1 = (const float*)d_in[3];
  const float* aS1= (const float*)d_in[4];
  const float* aD1= (const float*)d_in[5];
  const float* b1 = (const float*)d_in[6];
  const float* W2 = (const float*)d_in[7];
  const float* aS2= (const float*)d_in[8];
  const float* aD2= (const float*)d_in[9];
  const float* b2 = (const float*)d_in[10];
  const float* W3 = (const float*)d_in[11];
  const float* aS3= (const float*)d_in[12];
  const float* aD3= (const float*)d_in[13];
  const float* b3 = (const float*)d_in[14];
  const float* Wna1=(const float*)d_in[15];
  const float* bna1=(const float*)d_in[16];
  const float* Wna2=(const float*)d_in[17];
  const float* bna2=(const float*)d_in[18];
  const float* Wc1=(const float*)d_in[19];
  const float* bc1=(const float*)d_in[20];
  const float* Wc2=(const float*)d_in[21];
  const float* bc2=(const float*)d_in[22];
  const float* Wc3=(const float*)d_in[23];
  const float* bc3=(const float*)d_in[24];
  float* out = (float*)d_out;

  // workspace carve-out
  char* w = (char*)d_ws;
  size_t off = 0;
  auto alloc = [&](size_t bytes) {
    void* p = w + off;
    off = (off + bytes + 255) & ~(size_t)255;
    return p;
  };
  u16* xb   = (u16*)alloc((size_t)NP * 32 * 2);        // padded bf16 input
  u16* bufA = (u16*)alloc((size_t)NP * 256 * 2);       // h1 / h2 / h3
  u16* bufB = (u16*)alloc((size_t)NP * 256 * 2);       // y1 / y2 / x3(fp32)
  u16* W1t  = (u16*)alloc((size_t)256 * 32 * 2);
  u16* W2t  = (u16*)alloc((size_t)256 * 256 * 2);
  u16* W3t  = (u16*)alloc((size_t)64 * 256 * 2);
  float* asb  = (float*)alloc((size_t)NP * 4 * 4);
  float* adb  = (float*)alloc((size_t)NP * 4 * 4);
  float* nab  = (float*)alloc((size_t)NN * 4);
  int* rowp = (int*)alloc((size_t)(NN + 1) * 4);
  // cntb, curb, gsum contiguous -> single memset
  int* cntb = (int*)alloc((size_t)NN * 4);
  int* curb = (int*)alloc((size_t)NN * 4);
  float* gsum = (float*)alloc(256);
  size_t zspan = (size_t)((char*)gsum + 256 - (char*)cntb);
  int* colb = (int*)alloc((size_t)ETOT * 4);
  int* part = (int*)alloc(128 * 4);
  float* ppsum = (float*)alloc((size_t)PC * BB * 64 * 4);
  float* ppmax = (float*)alloc((size_t)PC * BB * 64 * 4);
  float* x3 = (float*)bufB;  // reuse (y2 dead after gemm3)
  (void)ws_size; (void)in_sizes; (void)n_in; (void)out_size;

  hipMemsetAsync(cntb, 0, zspan, stream);

  // CSR by dst (self-loops appended)
  count_kernel<<<(ETOT + 255) / 256, 256, 0, stream>>>(ei, cntb);
  scan1_kernel<<<98, 512, 0, stream>>>(cntb, rowp, part);
  scan2_kernel<<<1, 128, 0, stream>>>(part, rowp);
  scan3_kernel<<<98, 512, 0, stream>>>(rowp, part);
  fill_kernel<<<(ETOT + 255) / 256, 256, 0, stream>>>(ei, rowp, curb, colb);

  // fused dtype prep
  const int PREP_TOT = NP * 32 + 8192 + 65536 + 16384;
  prep_kernel<<<(PREP_TOT + 255) / 256, 256, 0, stream>>>(x, W1, W2, W3, xb, W1t, W2t, W3t);

  const int GX = NP / 128;  // 392
  // layer 1: 15(->32) -> 256  (scores fused into epilogue)
  gemm_bf16_kernel<32><<<dim3(GX, 4), 256, 0, stream>>>(xb, W1t, bufA, 32, 256,
                                                        aS1, aD1, asb, adb, 4);
  agg4_kernel<<<12500, 256, 0, stream>>>(bufA, asb, adb, rowp, colb, b1, bufB);
  // layer 2: 256 -> 256
  gemm_bf16_kernel<64><<<dim3(GX, 4), 256, 0, stream>>>(bufB, W2t, bufA, 256, 256,
                                                        aS2, aD2, asb, adb, 4);
  agg4_kernel<<<12500, 256, 0, stream>>>(bufA, asb, adb, rowp, colb, b2, bufB);
  // layer 3: 256 -> 64
  gemm_bf16_kernel<64><<<dim3(GX, 1), 256, 0, stream>>>(bufB, W3t, bufA, 256, 64,
                                                        aS3, aD3, asb, adb, 1);
  agg1_kernel<<<12500, 256, 0, stream>>>(bufA, asb, adb, rowp, colb, b3, x3);

  // node attention softmax over all N (MLP + exp + sum fused)
  na_kernel<<<(NN + 255) / 256, 256, 0, stream>>>(x3, Wna1, bna1, Wna2, bna2, nab, gsum);
  na_write_kernel<<<(NN + 255) / 256, 256, 0, stream>>>(nab, gsum, out + BB);

  // pooling (two-stage, fold fused with classifier)
  pool1_kernel<<<dim3(BB, PC), 256, 0, stream>>>(x3, batch, ppsum, ppmax);
  pool2cls_kernel<<<BB, 128, 0, stream>>>(ppsum, ppmax, batch, Wc1, bc1, Wc2, bc2,
                                          Wc3, bc3, out);
}

// Round 8
// 374.957 us; speedup vs baseline: 1.2688x; 1.0440x over previous
//
#include <hip/hip_runtime.h>
#include <math.h>

#define NN 50000
#define NP 50176   // NN padded to 392*128 for guard-free GEMM
#define EE 800000
#define ETOT (EE + NN)
#define BB 50
#define PC 16  // pooling chunks per graph

typedef unsigned short u16;
typedef unsigned char u8;
typedef __attribute__((ext_vector_type(8))) short short8;
typedef __attribute__((ext_vector_type(4))) float floatx4;
typedef __attribute__((ext_vector_type(2))) float floatx2;

__device__ __forceinline__ float b2f(u16 u) {
  return __int_as_float(((int)u) << 16);
}
__device__ __forceinline__ u16 f2b(float f) {
  unsigned u = __float_as_uint(f);
  unsigned r = (u + 0x7fffu + ((u >> 16) & 1u)) >> 16;
  return (u16)r;
}
__device__ __forceinline__ u8 f2f8(float v) {
  return (u8)(__builtin_amdgcn_cvt_pk_fp8_f32(v, v, 0, false) & 0xFF);
}
__device__ __forceinline__ float readlane_f(float v, int l) {
  return __int_as_float(__builtin_amdgcn_readlane(__float_as_int(v), l));
}
// bf16 pair -> f32 (1 VALU each)
__device__ __forceinline__ float blo(unsigned w) { return __uint_as_float(w << 16); }
__device__ __forceinline__ float bhi(unsigned w) { return __uint_as_float(w & 0xffff0000u); }

// ---------------- CSR build ----------------
__global__ void count_kernel(const int* __restrict__ ei, int* __restrict__ cnt) {
  int e = blockIdx.x * blockDim.x + threadIdx.x;
  if (e >= ETOT) return;
  int d = (e < EE) ? ei[EE + e] : (e - EE);
  atomicAdd(&cnt[d], 1);
}

// stage 1: block-local exclusive scan (98 blocks x 512)
__global__ void scan1_kernel(const int* __restrict__ cnt, int* __restrict__ rowp,
                             int* __restrict__ part) {
  __shared__ int s[512];
  int t = threadIdx.x;
  int i = blockIdx.x * 512 + t;
  int v = (i < NN) ? cnt[i] : 0;
  s[t] = v;
  __syncthreads();
  for (int off = 1; off < 512; off <<= 1) {
    int add = (t >= off) ? s[t - off] : 0;
    __syncthreads();
    s[t] += add;
    __syncthreads();
  }
  if (i < NN) rowp[i] = s[t] - v;  // exclusive within block
  if (t == 511) part[blockIdx.x] = s[511];
}

// stage 2: parallel scan over the 98 block partials (one 128-thread block)
__global__ void scan2_kernel(int* __restrict__ part, int* __restrict__ rowp) {
  __shared__ int s[128];
  int t = threadIdx.x;
  int v = (t < 98) ? part[t] : 0;
  s[t] = v;
  __syncthreads();
  for (int off = 1; off < 128; off <<= 1) {
    int add = (t >= off) ? s[t - off] : 0;
    __syncthreads();
    s[t] += add;
    __syncthreads();
  }
  if (t < 98) part[t] = s[t] - v;   // exclusive
  if (t == 97) rowp[NN] = s[97];    // total == ETOT
}

// stage 3: add block offset
__global__ void scan3_kernel(int* __restrict__ rowp, const int* __restrict__ part) {
  int i = blockIdx.x * 512 + threadIdx.x;
  if (i < NN) rowp[i] += part[blockIdx.x];
}

__global__ void fill_kernel(const int* __restrict__ ei, const int* __restrict__ rowp,
                            int* __restrict__ cur, int* __restrict__ col) {
  int e = blockIdx.x * blockDim.x + threadIdx.x;
  if (e >= ETOT) return;
  int s, d;
  if (e < EE) { s = ei[e]; d = ei[EE + e]; } else { s = e - EE; d = s; }
  int p = atomicAdd(&cur[d], 1);
  col[rowp[d] + p] = s;
}

// ---------------- fused dtype prep (xb + W1t + W2t + W3t) ----------------
__global__ void prep_kernel(const float* __restrict__ x, const float* __restrict__ W1,
                            const float* __restrict__ W2, const float* __restrict__ W3,
                            u16* __restrict__ xb, u16* __restrict__ W1t,
                            u16* __restrict__ W2t, u16* __restrict__ W3t) {
  const int T0 = NP * 32, T1 = T0 + 8192, T2 = T1 + 65536, T3 = T2 + 16384;
  int i = blockIdx.x * 256 + threadIdx.x;
  if (i < T0) {
    int n = i >> 5, c = i & 31;
    xb[i] = (n < NN && c < 15) ? f2b(x[n * 15 + c]) : (u16)0;
  } else if (i < T1) {
    int j = i - T0, n = j >> 5, k = j & 31;
    W1t[j] = (k < 15) ? f2b(W1[k * 256 + n]) : (u16)0;
  } else if (i < T2) {
    int j = i - T1, n = j >> 8, k = j & 255;
    W2t[j] = f2b(W2[k * 256 + n]);
  } else if (i < T3) {
    int j = i - T2, n = j >> 8, k = j & 255;
    W3t[j] = f2b(W3[k * 64 + n]);
  }
}

// ---------------- bf16 MFMA GEMM + fused attention-score epilogue ----------------
// C[NP,N] = A[NP,K] @ Bt[N,K]^T.  BM=128, BN=64, template BK (32|64).
// F8: emit h as fp8 e4m3 (gather payload for agg4); else bf16.
// Block (bx,by) covers rows R0..R0+127 and cols of head `by` exactly, so the
// per-node scores as/ad for head by are reduced in-epilogue (shfl + LDS).
template <int BK, bool F8>
__global__ __launch_bounds__(256) void gemm_bf16_kernel(
    const u16* __restrict__ A, const u16* __restrict__ Bt, u16* __restrict__ C,
    u8* __restrict__ C8, int K, int N, const float* __restrict__ aS,
    const float* __restrict__ aD, float* __restrict__ as_o,
    float* __restrict__ ad_o, int Hh) {
  __shared__ u16 Al[128][BK + 8];
  __shared__ u16 Bl[64][BK + 8];
  __shared__ float sS[4][64], sD[4][64];
  int R0 = blockIdx.x * 128, C0 = blockIdx.y * 64;
  int wid = threadIdx.x >> 6, lane = threadIdx.x & 63;
  int wr = (wid >> 1) * 64, wc = (wid & 1) * 32;
  int lrow = lane & 15, lk8 = (lane >> 4) * 8;
  int rq = (lane >> 4) * 4;
  const int Q4 = BK / 4;           // ushort4 per row
  const int nA = 128 * Q4, nB = 64 * Q4;
  floatx4 acc[4][2];
#pragma unroll
  for (int i = 0; i < 4; ++i)
#pragma unroll
    for (int j = 0; j < 2; ++j) acc[i][j] = (floatx4){0.f, 0.f, 0.f, 0.f};

  for (int k0 = 0; k0 < K; k0 += BK) {
    for (int c = threadIdx.x; c < nA + nB; c += 256) {
      if (c < nA) {
        int r = c / Q4, o = (c % Q4) * 4;
        *(ushort4*)&Al[r][o] = *(const ushort4*)&A[(size_t)(R0 + r) * K + k0 + o];
      } else {
        int c2 = c - nA;
        int r = c2 / Q4, o = (c2 % Q4) * 4;
        *(ushort4*)&Bl[r][o] = *(const ushort4*)&Bt[(size_t)(C0 + r) * K + k0 + o];
      }
    }
    __syncthreads();
#pragma unroll
    for (int ks = 0; ks < BK / 32; ++ks) {
      short8 a[4], b[2];
#pragma unroll
      for (int i = 0; i < 4; ++i) a[i] = *(const short8*)&Al[wr + i * 16 + lrow][ks * 32 + lk8];
#pragma unroll
      for (int j = 0; j < 2; ++j) b[j] = *(const short8*)&Bl[wc + j * 16 + lrow][ks * 32 + lk8];
#pragma unroll
      for (int i = 0; i < 4; ++i)
#pragma unroll
        for (int j = 0; j < 2; ++j)
          acc[i][j] = __builtin_amdgcn_mfma_f32_16x16x32_bf16(a[i], b[j], acc[i][j], 0, 0, 0);
    }
    __syncthreads();
  }
  // h write: fp8 (gather payload) or bf16
#pragma unroll
  for (int i = 0; i < 4; ++i)
#pragma unroll
    for (int j = 0; j < 2; ++j)
#pragma unroll
      for (int q = 0; q < 4; ++q) {
        int gr = R0 + wr + i * 16 + rq + q;
        int gc = C0 + wc + j * 16 + lrow;
        if constexpr (F8)
          C8[(size_t)gr * N + gc] = f2f8(acc[i][j][q]);
        else
          C[(size_t)gr * N + gc] = f2b(acc[i][j][q]);
      }
  // fused score epilogue: per-row dot with aS/aD for head `by`
  int hb = blockIdx.y * 64;
  float wS0 = aS[hb + wc + lrow], wS1 = aS[hb + wc + 16 + lrow];
  float wD0 = aD[hb + wc + lrow], wD1 = aD[hb + wc + 16 + lrow];
#pragma unroll
  for (int i = 0; i < 4; ++i)
#pragma unroll
    for (int q = 0; q < 4; ++q) {
      float vS = acc[i][0][q] * wS0 + acc[i][1][q] * wS1;
      float vD = acc[i][0][q] * wD0 + acc[i][1][q] * wD1;
#pragma unroll
      for (int o = 8; o; o >>= 1) {
        vS += __shfl_xor(vS, o, 64);
        vD += __shfl_xor(vD, o, 64);
      }
      if (lrow == 0) {
        int rl = i * 16 + rq + q;
        sS[wid][rl] = vS;
        sD[wid][rl] = vD;
      }
    }
  __syncthreads();
  if (threadIdx.x < 128) {
    int p = threadIdx.x >> 6, r = threadIdx.x & 63;
    int gr = R0 + p * 64 + r;
    as_o[(size_t)gr * Hh + blockIdx.y] = sS[2 * p][r] + sS[2 * p + 1][r];
    ad_o[(size_t)gr * Hh + blockIdx.y] = sD[2 * p][r] + sD[2 * p + 1][r];
  }
}

// ---------------- single-pass softmax-aggregate, H=4, fp8 h -> bf16 out ----------------
// Lane owns channels [4*lane..4*lane+3]: one dword of fp8 per edge (256B/row).
__global__ __launch_bounds__(256) void agg4_kernel(
    const u8* __restrict__ h8, const float* __restrict__ as_i,
    const float* __restrict__ ad_i, const int* __restrict__ rowp,
    const int* __restrict__ col, const float* __restrict__ bias,
    u16* __restrict__ xo) {
  __shared__ float exs[4][64][4];  // [wave][edge-slot][head]
  int wid = threadIdx.x >> 6, lane = threadIdx.x & 63;
  int d = blockIdx.x * 4 + wid;
  int rp0 = rowp[d], deg = rowp[d + 1] - rp0;
  float4 add = *(const float4*)&ad_i[(size_t)d * 4];
  int hj = lane >> 4;  // head of this lane's 4 channels
  int lq = lane << 2;  // first channel owned by this lane
  float acc0 = 0.f, acc1 = 0.f, acc2 = 0.f, acc3 = 0.f;
  float den0 = 0.f, den1 = 0.f, den2 = 0.f, den3 = 0.f;

  for (int base = 0; base < deg; base += 64) {
    int i = base + lane;
    bool valid = i < deg;
    int s = valid ? col[rp0 + i] : 0;
    float4 asv = *(const float4*)&as_i[(size_t)s * 4];
    float e0 = asv.x + add.x, e1 = asv.y + add.y, e2 = asv.z + add.z, e3 = asv.w + add.w;
    e0 = (e0 > 0.f) ? e0 : 0.2f * e0;
    e1 = (e1 > 0.f) ? e1 : 0.2f * e1;
    e2 = (e2 > 0.f) ? e2 : 0.2f * e2;
    e3 = (e3 > 0.f) ? e3 : 0.2f * e3;
    float x0 = valid ? __expf(e0) : 0.f;
    float x1 = valid ? __expf(e1) : 0.f;
    float x2 = valid ? __expf(e2) : 0.f;
    float x3 = valid ? __expf(e3) : 0.f;
    den0 += x0; den1 += x1; den2 += x2; den3 += x3;
    *(float4*)&exs[wid][lane][0] = make_float4(x0, x1, x2, x3);
    __threadfence_block();  // order ds_write before the broadcast ds_reads
    int cnt = min(64, deg - base);
    int k8 = cnt & ~7;
    for (int k = 0; k < k8; k += 8) {
      unsigned wv[8];
      float qv[8];
#pragma unroll
      for (int u = 0; u < 8; ++u) {
        int sk = __builtin_amdgcn_readlane(s, k + u);
        qv[u] = exs[wid][k + u][hj];
        wv[u] = *(const unsigned*)&h8[(size_t)sk * 256 + lq];
      }
#pragma unroll
      for (int u = 0; u < 8; ++u) {
        floatx2 lo = __builtin_amdgcn_cvt_pk_f32_fp8(wv[u], false);
        floatx2 hi = __builtin_amdgcn_cvt_pk_f32_fp8(wv[u], true);
        acc0 += qv[u] * lo.x;
        acc1 += qv[u] * lo.y;
        acc2 += qv[u] * hi.x;
        acc3 += qv[u] * hi.y;
      }
    }
    for (int k = k8; k < cnt; ++k) {
      int sk = __builtin_amdgcn_readlane(s, k);
      float qk = exs[wid][k][hj];
      unsigned wv = *(const unsigned*)&h8[(size_t)sk * 256 + lq];
      floatx2 lo = __builtin_amdgcn_cvt_pk_f32_fp8(wv, false);
      floatx2 hi = __builtin_amdgcn_cvt_pk_f32_fp8(wv, true);
      acc0 += qk * lo.x;
      acc1 += qk * lo.y;
      acc2 += qk * hi.x;
      acc3 += qk * hi.y;
    }
  }
#pragma unroll
  for (int o = 32; o; o >>= 1) {
    den0 += __shfl_xor(den0, o, 64);
    den1 += __shfl_xor(den1, o, 64);
    den2 += __shfl_xor(den2, o, 64);
    den3 += __shfl_xor(den3, o, 64);
  }
  float den = (hj == 0) ? den0 : (hj == 1) ? den1 : (hj == 2) ? den2 : den3;
  float inv = 1.f / den;
  float4 bv = *(const float4*)&bias[lq];
  float v0 = acc0 * inv + bv.x;
  float v1 = acc1 * inv + bv.y;
  float v2 = acc2 * inv + bv.z;
  float v3 = acc3 * inv + bv.w;
  v0 = (v0 > 0.f) ? v0 : expm1f(v0);
  v1 = (v1 > 0.f) ? v1 : expm1f(v1);
  v2 = (v2 > 0.f) ? v2 : expm1f(v2);
  v3 = (v3 > 0.f) ? v3 : expm1f(v3);
  ushort4 o4;
  o4.x = f2b(v0); o4.y = f2b(v1); o4.z = f2b(v2); o4.w = f2b(v3);
  ((ushort4*)xo)[(size_t)d * 64 + lane] = o4;
}

// ---------------- single-pass softmax-aggregate, H=1, bf16 h -> fp32 out ----------------
__global__ __launch_bounds__(256) void agg1_kernel(
    const u16* __restrict__ h, const float* __restrict__ as_i,
    const float* __restrict__ ad_i, const int* __restrict__ rowp,
    const int* __restrict__ col, const float* __restrict__ bias,
    float* __restrict__ xo) {
  int wid = threadIdx.x >> 6, lane = threadIdx.x & 63;
  int d = blockIdx.x * 4 + wid;
  int rp0 = rowp[d], deg = rowp[d + 1] - rp0;
  float add = ad_i[d];
  float acc = 0.f, den = 0.f;
  for (int base = 0; base < deg; base += 64) {
    int i = base + lane;
    bool valid = i < deg;
    int s = valid ? col[rp0 + i] : 0;
    float e = as_i[s] + add;
    e = (e > 0.f) ? e : 0.2f * e;
    float ex = valid ? __expf(e) : 0.f;
    den += ex;
    int cnt = min(64, deg - base);
    int k8 = cnt & ~7;
    for (int k = 0; k < k8; k += 8) {
      int sA[8];
      float qA[8], hv[8];
#pragma unroll
      for (int u = 0; u < 8; ++u) {
        sA[u] = __builtin_amdgcn_readlane(s, k + u);
        qA[u] = readlane_f(ex, k + u);
      }
#pragma unroll
      for (int u = 0; u < 8; ++u) hv[u] = b2f(h[(size_t)sA[u] * 64 + lane]);
      float p0 = qA[0] * hv[0] + qA[1] * hv[1];
      float p1 = qA[2] * hv[2] + qA[3] * hv[3];
      float p2 = qA[4] * hv[4] + qA[5] * hv[5];
      float p3 = qA[6] * hv[6] + qA[7] * hv[7];
      acc += (p0 + p1) + (p2 + p3);
    }
    for (int k = k8; k < cnt; ++k) {
      int sk = __builtin_amdgcn_readlane(s, k);
      float qk = readlane_f(ex, k);
      acc += qk * b2f(h[(size_t)sk * 64 + lane]);
    }
  }
#pragma unroll
  for (int o = 32; o; o >>= 1) den += __shfl_xor(den, o, 64);
  float v = acc / den + bias[lane];
  v = (v > 0.f) ? v : expm1f(v);
  xo[(size_t)d * 64 + lane] = v;
}

// ---------------- node-attention MLP + fused exp/sum ----------------
__global__ void na_kernel(const float* __restrict__ x3, const float* __restrict__ W1,
                          const float* __restrict__ b1, const float* __restrict__ W2,
                          const float* __restrict__ b2, float* __restrict__ na,
                          float* __restrict__ gsum) {
  __shared__ float Ws[64 * 32];
  __shared__ float W2s[32];
  __shared__ float sred[4];
  for (int i = threadIdx.x; i < 2048; i += blockDim.x) Ws[i] = W1[i];
  if (threadIdx.x < 32) W2s[threadIdx.x] = W2[threadIdx.x];
  __syncthreads();
  int n = blockIdx.x * blockDim.x + threadIdx.x;
  float ez = 0.f;
  if (n < NN) {
    float hid[32];
#pragma unroll
    for (int j = 0; j < 32; ++j) hid[j] = b1[j];
    const float4* x4 = (const float4*)&x3[(size_t)n * 64];
    for (int kk = 0; kk < 16; ++kk) {
      float4 xv = x4[kk];
#pragma unroll
      for (int j = 0; j < 32; ++j) {
        hid[j] += xv.x * Ws[(kk * 4 + 0) * 32 + j];
        hid[j] += xv.y * Ws[(kk * 4 + 1) * 32 + j];
        hid[j] += xv.z * Ws[(kk * 4 + 2) * 32 + j];
        hid[j] += xv.w * Ws[(kk * 4 + 3) * 32 + j];
      }
    }
    float z = b2[0];
#pragma unroll
    for (int j = 0; j < 32; ++j) z += fmaxf(hid[j], 0.f) * W2s[j];
    ez = __expf(z);
    na[n] = ez;
  }
  float acc = ez;
  for (int o = 32; o; o >>= 1) acc += __shfl_xor(acc, o, 64);
  int wid = threadIdx.x >> 6, lane = threadIdx.x & 63;
  if (lane == 0) sred[wid] = acc;
  __syncthreads();
  if (threadIdx.x == 0) atomicAdd(gsum, sred[0] + sred[1] + sred[2] + sred[3]);
}

__global__ void na_write_kernel(const float* __restrict__ na, const float* __restrict__ gsum,
                                float* __restrict__ out) {
  int n = blockIdx.x * blockDim.x + threadIdx.x;
  if (n >= NN) return;
  out[n] = na[n] / gsum[0];
}

// ---------------- pooling stage 1: partial sum/max per (graph, chunk) ----------------
__global__ void pool1_kernel(const float* __restrict__ x3, const int* __restrict__ batch,
                             float* __restrict__ ppsum, float* __restrict__ ppmax) {
  int b = blockIdx.x, c = blockIdx.y;
  int lane = threadIdx.x & 63, wid = threadIdx.x >> 6;
  int lo = 0, hi = NN;
  while (lo < hi) { int m = (lo + hi) >> 1; if (batch[m] < b) lo = m + 1; else hi = m; }
  int start = lo;
  lo = start; hi = NN;
  while (lo < hi) { int m = (lo + hi) >> 1; if (batch[m] < b + 1) lo = m + 1; else hi = m; }
  int end = lo;
  int len = end - start;
  int c0 = start + (int)((long)len * c / PC);
  int c1 = start + (int)((long)len * (c + 1) / PC);
  float acc = 0.f, mx = -INFINITY;
  for (int n = c0 + wid; n < c1; n += 4) {
    float v = x3[(size_t)n * 64 + lane];
    acc += v;
    mx = fmaxf(mx, v);
  }
  __shared__ float ssum[4][64], smax[4][64];
  ssum[wid][lane] = acc;
  smax[wid][lane] = mx;
  __syncthreads();
  if (wid == 0) {
    acc = ssum[0][lane] + ssum[1][lane] + ssum[2][lane] + ssum[3][lane];
    mx = fmaxf(fmaxf(smax[0][lane], smax[1][lane]), fmaxf(smax[2][lane], smax[3][lane]));
    size_t o = ((size_t)c * BB + b) * 64 + lane;
    ppsum[o] = acc;
    ppmax[o] = mx;
  }
}

// ---------------- pooling fold + graph classifier (fused) ----------------
__global__ void pool2cls_kernel(const float* __restrict__ ppsum, const float* __restrict__ ppmax,
                                const int* __restrict__ batch, const float* __restrict__ Wc1,
                                const float* __restrict__ bc1, const float* __restrict__ Wc2,
                                const float* __restrict__ bc2, const float* __restrict__ Wc3,
                                const float* __restrict__ bc3, float* __restrict__ out) {
  __shared__ float g[128], h1[128], h2[64], scnt;
  int b = blockIdx.x, t = threadIdx.x;
  if (t == 0) {
    int lo = 0, hi = NN;
    while (lo < hi) { int m = (lo + hi) >> 1; if (batch[m] < b) lo = m + 1; else hi = m; }
    int start = lo;
    lo = start; hi = NN;
    while (lo < hi) { int m = (lo + hi) >> 1; if (batch[m] < b + 1) lo = m + 1; else hi = m; }
    scnt = (float)(lo - start);
  }
  float s = 0.f, m = -INFINITY;
  if (t < 64) {
#pragma unroll
    for (int c = 0; c < PC; ++c) {
      size_t o = ((size_t)c * BB + b) * 64 + t;
      s += ppsum[o];
      m = fmaxf(m, ppmax[o]);
    }
  }
  __syncthreads();
  float cnt = scnt;
  if (t < 64) {
    g[t] = (cnt > 0.f) ? s / fmaxf(cnt, 1.f) : 0.f;
    g[64 + t] = (cnt > 0.f) ? m : 0.f;
  }
  __syncthreads();
  float v = bc1[t];
  for (int k = 0; k < 128; ++k) v += g[k] * Wc1[k * 128 + t];
  h1[t] = fmaxf(v, 0.f);
  __syncthreads();
  if (t < 64) {
    float v2 = bc2[t];
    for (int k = 0; k < 128; ++k) v2 += h1[k] * Wc2[k * 64 + t];
    h2[t] = fmaxf(v2, 0.f);
  }
  __syncthreads();
  if (t == 0) {
    float z = bc3[0];
    for (int k = 0; k < 64; ++k) z += h2[k] * Wc3[k];
    out[b] = 1.f / (1.f + expf(-z));
  }
}

extern "C" void kernel_launch(void* const* d_in, const int* in_sizes, int n_in,
                              void* d_out, int out_size, void* d_ws, size_t ws_size,
                              hipStream_t stream) {
  const float* x    = (const float*)d_in[0];
  const int*   ei   = (const int*)d_in[1];
  const int*   batch= (const int*)d_in[2];
  const float* W1 = (const float*)d_in[3];
  const float* aS1= (const float*)d_in[4];
  const float* aD1= (const float*)d_in[5];
  const float* b1 = (const float*)d_in[6];
  const float* W2 = (const float*)d_in[7];
  const float* aS2= (const float*)d_in[8];
  const float* aD2= (const float*)d_in[9];
  const float* b2 = (const float*)d_in[10];
  const float* W3 = (const float*)d_in[11];
  const float* aS3= (const float*)d_in[12];
  const float* aD3= (const float*)d_in[13];
  const float* b3 = (const float*)d_in[14];
  const float* Wna1=(const float*)d_in[15];
  const float* bna1=(const float*)d_in[16];
  const float* Wna2=(const float*)d_in[17];
  const float* bna2=(const float*)d_in[18];
  const float* Wc1=(const float*)d_in[19];
  const float* bc1=(const float*)d_in[20];
  const float* Wc2=(const float*)d_in[21];
  const float* bc2=(const float*)d_in[22];
  const float* Wc3=(const float*)d_in[23];
  const float* bc3=(const float*)d_in[24];
  float* out = (float*)d_out;

  // workspace carve-out
  char* w = (char*)d_ws;
  size_t off = 0;
  auto alloc = [&](size_t bytes) {
    void* p = w + off;
    off = (off + bytes + 255) & ~(size_t)255;
    return p;
  };
  u16* xb   = (u16*)alloc((size_t)NP * 32 * 2);        // padded bf16 input
  u16* bufA = (u16*)alloc((size_t)NP * 256 * 2);       // h3 (bf16)
  u16* bufB = (u16*)alloc((size_t)NP * 256 * 2);       // y1 / y2 / x3(fp32)
  u8*  h8   = (u8*)alloc((size_t)NP * 256);            // fp8 h1 / h2 (gather payload)
  u16* W1t  = (u16*)alloc((size_t)256 * 32 * 2);
  u16* W2t  = (u16*)alloc((size_t)256 * 256 * 2);
  u16* W3t  = (u16*)alloc((size_t)64 * 256 * 2);
  float* asb  = (float*)alloc((size_t)NP * 4 * 4);
  float* adb  = (float*)alloc((size_t)NP * 4 * 4);
  float* nab  = (float*)alloc((size_t)NN * 4);
  int* rowp = (int*)alloc((size_t)(NN + 1) * 4);
  // cntb, curb, gsum contiguous -> single memset
  int* cntb = (int*)alloc((size_t)NN * 4);
  int* curb = (int*)alloc((size_t)NN * 4);
  float* gsum = (float*)alloc(256);
  size_t zspan = (size_t)((char*)gsum + 256 - (char*)cntb);
  int* colb = (int*)alloc((size_t)ETOT * 4);
  int* part = (int*)alloc(128 * 4);
  float* ppsum = (float*)alloc((size_t)PC * BB * 64 * 4);
  float* ppmax = (float*)alloc((size_t)PC * BB * 64 * 4);
  float* x3 = (float*)bufB;  // reuse (y2 dead after gemm3)
  (void)ws_size; (void)in_sizes; (void)n_in; (void)out_size;

  hipMemsetAsync(cntb, 0, zspan, stream);

  // CSR by dst (self-loops appended)
  count_kernel<<<(ETOT + 255) / 256, 256, 0, stream>>>(ei, cntb);
  scan1_kernel<<<98, 512, 0, stream>>>(cntb, rowp, part);
  scan2_kernel<<<1, 128, 0, stream>>>(part, rowp);
  scan3_kernel<<<98, 512, 0, stream>>>(rowp, part);
  fill_kernel<<<(ETOT + 255) / 256, 256, 0, stream>>>(ei, rowp, curb, colb);

  // fused dtype prep
  const int PREP_TOT = NP * 32 + 8192 + 65536 + 16384;
  prep_kernel<<<(PREP_TOT + 255) / 256, 256, 0, stream>>>(x, W1, W2, W3, xb, W1t, W2t, W3t);

  const int GX = NP / 128;  // 392
  // layer 1: 15(->32) -> 256  (scores fused; h in fp8)
  gemm_bf16_kernel<32, true><<<dim3(GX, 4), 256, 0, stream>>>(
      xb, W1t, nullptr, h8, 32, 256, aS1, aD1, asb, adb, 4);
  agg4_kernel<<<12500, 256, 0, stream>>>(h8, asb, adb, rowp, colb, b1, bufB);
  // layer 2: 256 -> 256
  gemm_bf16_kernel<64, true><<<dim3(GX, 4), 256, 0, stream>>>(
      bufB, W2t, nullptr, h8, 256, 256, aS2, aD2, asb, adb, 4);
  agg4_kernel<<<12500, 256, 0, stream>>>(h8, asb, adb, rowp, colb, b2, bufB);
  // layer 3: 256 -> 64 (h3 stays bf16, output-adjacent)
  gemm_bf16_kernel<64, false><<<dim3(GX, 1), 256, 0, stream>>>(
      bufB, W3t, bufA, nullptr, 256, 64, aS3, aD3, asb, adb, 1);
  agg1_kernel<<<12500, 256, 0, stream>>>(bufA, asb, adb, rowp, colb, b3, x3);

  // node attention softmax over all N (MLP + exp + sum fused)
  na_kernel<<<(NN + 255) / 256, 256, 0, stream>>>(x3, Wna1, bna1, Wna2, bna2, nab, gsum);
  na_write_kernel<<<(NN + 255) / 256, 256, 0, stream>>>(nab, gsum, out + BB);

  // pooling (two-stage, fold fused with classifier)
  pool1_kernel<<<dim3(BB, PC), 256, 0, stream>>>(x3, batch, ppsum, ppmax);
  pool2cls_kernel<<<BB, 128, 0, stream>>>(ppsum, ppmax, batch, Wc1, bc1, Wc2, bc2,
                                          Wc3, bc3, out);
}